// Round 6
// baseline (256.509 us; speedup 1.0000x reference)
//
#include <hip/hip_runtime.h>
#include <cstdint>
#include <cstddef>

#define BPTS    131072
#define D_DIM   128
#define G_GR    128
#define NL      8
#define NSLC    16                 // slices per group -> 2048 heavy blocks
#define PERMBUF 128                // max slice len ~72
#define NBLK_S  64                 // sort blocks
#define PPB     (BPTS / NBLK_S)    // 2048 contiguous points per sort block

// ---------------------------------------------------------------------------
// k_hist: per-block histogram of group ids -> hblk[blk][128]
// ---------------------------------------------------------------------------
__global__ __launch_bounds__(256) void k_hist(const int* __restrict__ sub,
                                              const int* __restrict__ lab,
                                              int* __restrict__ hblk) {
    __shared__ int h[G_GR];
    int t = threadIdx.x, blk = blockIdx.x;
    if (t < G_GR) h[t] = 0;
    __syncthreads();
    int b0 = blk * PPB;
    for (int i = t; i < PPB; i += 256)
        atomicAdd(&h[sub[b0 + i] * NL + lab[b0 + i]], 1);
    __syncthreads();
    if (t < G_GR) hblk[blk * G_GR + t] = h[t];
}

// ---------------------------------------------------------------------------
// k_scatter: per-block LDS bucket sort, then COALESCED run writes to perm
// (runs of ~16 ints = 64 B vs R5's random 4 B scatters). Prefix over hblk
// recomputed per block (deterministic). Block 0 publishes counts/offsets.
// ---------------------------------------------------------------------------
__global__ __launch_bounds__(256) void k_scatter(const int* __restrict__ sub,
                                                 const int* __restrict__ lab,
                                                 const int* __restrict__ hblk,
                                                 int* __restrict__ counts,
                                                 int* __restrict__ offsets,
                                                 float* __restrict__ countsf,
                                                 int* __restrict__ perm) {
    __shared__ int lcnt[G_GR];     // local bucket counts
    __shared__ int loff[G_GR];     // local exclusive prefix
    __shared__ int gbase[G_GR];    // global dest base for this block's runs
    __shared__ int ids[PPB];       // bucketed point ids   (8 KB)
    __shared__ int gslot[PPB];     // group id per slot    (8 KB)
    int t = threadIdx.x, blk = blockIdx.x;

    if (t < G_GR) lcnt[t] = 0;
    __syncthreads();

    // phase A: local histogram, remember (g, rank) per owned point
    int b0 = blk * PPB;
    int garr[PPB / 256], carr[PPB / 256];
#pragma unroll
    for (int r = 0; r < PPB / 256; ++r) {
        int i = b0 + r * 256 + t;
        int g = sub[i] * NL + lab[i];
        garr[r] = g;
        carr[r] = atomicAdd(&lcnt[g], 1);
    }
    __syncthreads();

    // phase B: local prefix + global base from hblk; publish on block 0
    if (t < G_GR) {
        int o = 0;
        for (int j = 0; j < t; ++j) o += lcnt[j];
        loff[t] = o;
        int tt = 0, mine = 0;
        for (int b = 0; b < NBLK_S; ++b) {
            int v = hblk[b * G_GR + t];
            tt += v;
            if (b < blk) mine += v;
        }
        if (blk == 0) {
            counts[t]  = tt;
            countsf[t] = 2.0f * (float)tt;
        }
        // offsets[t] = global exclusive prefix of totals
        // compute via second serial loop over groups < t using hblk totals
        // (recompute totals per j is O(G*NBLK) per thread -> too slow; instead
        //  store tt in lcnt? lcnt still needed. Use gbase as scratch first.)
        gbase[t] = tt;     // stash totals
    }
    __syncthreads();
    if (t < G_GR) {
        int off = 0;
        for (int j = 0; j < t; ++j) off += gbase[j];   // totals stash
        if (blk == 0) offsets[t] = off;
        int mine = 0;
        for (int b = 0; b < blk; ++b) mine += hblk[b * G_GR + t];
        gbase[t] = off + mine;     // now the real dest base
    }
    __syncthreads();

    // phase C: place into LDS buckets
#pragma unroll
    for (int r = 0; r < PPB / 256; ++r) {
        int slot = loff[garr[r]] + carr[r];
        ids[slot]   = b0 + r * 256 + t;
        gslot[slot] = garr[r];
    }
    __syncthreads();

    // phase D: coalesced run writes
    for (int j = t; j < PPB; j += 256) {
        int g = gslot[j];
        perm[gbase[g] + (j - loff[g])] = ids[j];
    }
}

// ---------------------------------------------------------------------------
// k_psum: block (g,s) sums its slice (slen<=~72). Wave w owns points
// w*16..w*16+15: ALL 16 float4 loads issued back-to-back (16 KiB in flight,
// single waitcnt) before accumulating.
// ---------------------------------------------------------------------------
__global__ __launch_bounds__(256) void k_psum(const float4* __restrict__ X4,
                                              const int* __restrict__ perm,
                                              const int* __restrict__ offsets,
                                              const int* __restrict__ counts,
                                              float* __restrict__ part) {
    __shared__ int   pbuf[PERMBUF];
    __shared__ float red[4 * 256];
    int g = blockIdx.x >> 4, s = blockIdx.x & 15;
    int off = offsets[g], len = counts[g];
    int lo = off + (len * s) / NSLC;
    int hi = off + (len * (s + 1)) / NSLC;
    int slen = hi - lo;
    int t = threadIdx.x, lane = t & 63, w = t >> 6;

    for (int j = t; j < slen; j += 256) pbuf[j] = perm[lo + j];
    __syncthreads();

    float4 acc = make_float4(0.f, 0.f, 0.f, 0.f);
    for (int base = w * 16; base < slen; base += 64) {
        int idx[16];
#pragma unroll
        for (int u = 0; u < 16; ++u) {
            int j = base + u;
            idx[u] = pbuf[(j < slen) ? j : (slen - 1)];
        }
        float4 x[16];
#pragma unroll
        for (int u = 0; u < 16; ++u) x[u] = X4[(size_t)idx[u] * 64 + lane];
#pragma unroll
        for (int u = 0; u < 16; ++u) {
            if (base + u < slen) {
                acc.x += x[u].x; acc.y += x[u].y;
                acc.z += x[u].z; acc.w += x[u].w;
            }
        }
    }
    red[w * 256 + lane * 4 + 0] = acc.x;
    red[w * 256 + lane * 4 + 1] = acc.y;
    red[w * 256 + lane * 4 + 2] = acc.z;
    red[w * 256 + lane * 4 + 3] = acc.w;
    __syncthreads();
    if (t < 128) {                        // fold 4 wave copies + the two views
        float v = 0.f;
        for (int r = 0; r < 4; ++r)
            v += red[r * 256 + t] + red[r * 256 + t + 128];
        part[(size_t)blockIdx.x * 128 + t] = v;
    }
}

// ---------------------------------------------------------------------------
// k_dist: fused centroid reduce (slice 0 publishes centroid) + per-point
// ||x-c|| via 32-lane shfl butterfly; full-batch 16-point loads.
// ---------------------------------------------------------------------------
__global__ __launch_bounds__(256) void k_dist(const float4* __restrict__ X4,
                                              const int* __restrict__ perm,
                                              const int* __restrict__ offsets,
                                              const int* __restrict__ counts,
                                              const float* __restrict__ part,
                                              float* __restrict__ centroid,
                                              float* __restrict__ dpart) {
    __shared__ int   pbuf[PERMBUF];
    __shared__ float cen[D_DIM];
    __shared__ float wsum[4];
    int g = blockIdx.x >> 4, s = blockIdx.x & 15;
    int off = offsets[g], len = counts[g];
    int lo = off + (len * s) / NSLC;
    int hi = off + (len * (s + 1)) / NSLC;
    int slen = hi - lo;
    int t = threadIdx.x, lane = t & 63, w = t >> 6;

    if (t < D_DIM) {                      // fused k_reduce
        float v = 0.f;
        for (int s2 = 0; s2 < NSLC; ++s2)
            v += part[(size_t)(g * NSLC + s2) * 128 + t];
        float c = (len > 0) ? v / (2.0f * (float)len) : 0.f;
        cen[t] = c;
        if (s == 0) centroid[g * D_DIM + t] = c;
    }
    for (int j = t; j < slen; j += 256) pbuf[j] = perm[lo + j];
    __syncthreads();

    int cd = (lane & 31) * 4;
    float4 c = make_float4(cen[cd], cen[cd + 1], cen[cd + 2], cen[cd + 3]);

    float sacc = 0.f;
    for (int base = w * 16; base < slen; base += 64) {
        int idx[16];
#pragma unroll
        for (int u = 0; u < 16; ++u) {
            int j = base + u;
            idx[u] = pbuf[(j < slen) ? j : (slen - 1)];
        }
        float4 x[16];
#pragma unroll
        for (int u = 0; u < 16; ++u) x[u] = X4[(size_t)idx[u] * 64 + lane];
#pragma unroll
        for (int u = 0; u < 16; ++u) {
            float dx = x[u].x - c.x, dy = x[u].y - c.y;
            float dz = x[u].z - c.z, dw = x[u].w - c.w;
            float d = dx * dx + dy * dy + dz * dz + dw * dw;
#pragma unroll
            for (int m = 1; m <= 16; m <<= 1) d += __shfl_xor(d, m);
            if (base + u < slen) sacc += sqrtf(sqrtf(d));   // sqrt(||x-c||)
        }
    }
    float t2 = sacc + __shfl_xor(sacc, 32);   // fold the two views
    if (lane == 0) wsum[w] = t2;
    __syncthreads();
    if (t == 0) dpart[blockIdx.x] = wsum[0] + wsum[1] + wsum[2] + wsum[3];
}

// ---------------------------------------------------------------------------
// k_final: single block, 128 threads (thread t = group t).
// ---------------------------------------------------------------------------
__global__ __launch_bounds__(128) void k_final(const float* __restrict__ dpart,
                                               const float* __restrict__ countsf,
                                               const float* __restrict__ centroid,
                                               float* __restrict__ out) {
    __shared__ float srt[G_GR];
    __shared__ float red[G_GR];
    __shared__ float coc[D_DIM];
    int t = threadIdx.x;

    float ds = 0.f;
    for (int s = 0; s < NSLC; ++s) ds += dpart[t * NSLC + s];
    float cnt  = countsf[t];
    float dens = (cnt > 1.f) ? (ds / cnt) / logf(cnt + 10.f) : 0.f;

    red[t] = dens;
    __syncthreads();
    for (int s = 64; s > 0; s >>= 1) {
        if (t < s) red[t] = fmaxf(red[t], red[t + s]);
        __syncthreads();
    }
    float dmax = red[0];
    __syncthreads();
    if (!(cnt > 1.f)) dens = dmax;

    srt[t] = dens;
    __syncthreads();
    for (int k = 2; k <= G_GR; k <<= 1) {
        for (int j = k >> 1; j > 0; j >>= 1) {
            int ixj = t ^ j;
            if (ixj > t) {
                float a = srt[t], b = srt[ixj];
                bool up = ((t & k) == 0);
                if ((a > b) == up) { srt[t] = b; srt[ixj] = a; }
            }
            __syncthreads();
        }
    }
    double p10 = 0.10 * 127.0, p90 = 0.90 * 127.0;
    int   i10 = (int)p10,           i90 = (int)p90;
    float f10 = (float)(p10 - i10), f90 = (float)(p90 - i90);
    float lo = srt[i10] + f10 * (srt[i10 + 1] - srt[i10]);
    float hi = srt[i90] + f90 * (srt[i90 + 1] - srt[i90]);
    dens = fminf(fmaxf(dens, lo), hi);

    red[t] = dens;
    __syncthreads();
    for (int s = 64; s > 0; s >>= 1) {
        if (t < s) red[t] += red[t + s];
        __syncthreads();
    }
    float dmean = red[0] / 128.f;
    __syncthreads();
    dens = 0.1f * dens / dmean;

    float cs = 0.f;
    for (int g = 0; g < G_GR; ++g) cs += centroid[g * D_DIM + t];
    coc[t] = cs / 128.f;
    __syncthreads();

    float dot = 0.f;
    for (int d = 0; d < D_DIM; ++d) dot += centroid[t * D_DIM + d] * coc[d];
    float sim = expf(dot / dens);

    red[t] = sim;
    __syncthreads();
    for (int s = 64; s > 0; s >>= 1) {
        if (t < s) red[t] = fmaxf(red[t], red[t + s]);
        __syncthreads();
    }
    float smax = red[0];
    __syncthreads();
    red[t] = sim - smax;
    __syncthreads();
    for (int s = 64; s > 0; s >>= 1) {
        if (t < s) red[t] += red[t + s];
        __syncthreads();
    }
    if (t == 0) out[0] = -(red[0] / 128.f);
}

// ---------------------------------------------------------------------------
extern "C" void kernel_launch(void* const* d_in, const int* in_sizes, int n_in,
                              void* d_out, int out_size, void* d_ws, size_t ws_size,
                              hipStream_t stream) {
    const float4* X4      = (const float4*)d_in[0];
    const int*    subject = (const int*)d_in[1];
    const int*    labels  = (const int*)d_in[2];
    float*        out     = (float*)d_out;
    char*         ws      = (char*)d_ws;

    size_t o = 0;
    int*   hblk     = (int*)(ws + o);   o += (size_t)NBLK_S * G_GR * 4;     // 32 KiB
    int*   counts   = (int*)(ws + o);   o += 512;
    int*   offsets  = (int*)(ws + o);   o += 512;
    float* countsf  = (float*)(ws + o); o += 512;
    int*   perm     = (int*)(ws + o);   o += (size_t)BPTS * 4;              // 512 KiB
    float* part     = (float*)(ws + o); o += (size_t)G_GR * NSLC * 128 * 4; // 1 MiB
    float* centroid = (float*)(ws + o); o += (size_t)G_GR * D_DIM * 4;      // 64 KiB
    float* dpart    = (float*)(ws + o); o += (size_t)G_GR * NSLC * 4;       // 8 KiB

    k_hist   <<<NBLK_S, 256, 0, stream>>>(subject, labels, hblk);
    k_scatter<<<NBLK_S, 256, 0, stream>>>(subject, labels, hblk, counts, offsets, countsf, perm);
    k_psum   <<<G_GR * NSLC, 256, 0, stream>>>(X4, perm, offsets, counts, part);
    k_dist   <<<G_GR * NSLC, 256, 0, stream>>>(X4, perm, offsets, counts, part, centroid, dpart);
    k_final  <<<1, 128, 0, stream>>>(dpart, countsf, centroid, out);
}

// Round 7
// 256.467 us; speedup vs baseline: 1.0002x; 1.0002x over previous
//
#include <hip/hip_runtime.h>
#include <cstdint>
#include <cstddef>

#define BPTS   131072
#define D_DIM  128
#define G_GR   128
#define NL     8
#define NSLC   32                    // point-range slices for psum
#define RANGE  (BPTS / NSLC)         // 4096 points per psum range
#define DBLK   512                   // dist blocks
#define DPTS   (BPTS / DBLK)         // 256 points per dist block

// ---------------------------------------------------------------------------
// k_psum: block (g,s) scans point range s for group-g members (LDS compact,
// worst-case-safe cap = RANGE), then wave-per-point unroll-8 float4 gather,
// register accumulate. Writes part[blk][128] (views folded) + cnt[blk].
// No hist / no scatter / no perm.
// ---------------------------------------------------------------------------
__global__ __launch_bounds__(256) void k_psum(const float4* __restrict__ X4,
                                              const int* __restrict__ sub,
                                              const int* __restrict__ lab,
                                              float* __restrict__ part,
                                              int* __restrict__ cnt) {
    __shared__ int   list[RANGE];        // 16 KiB, worst-case safe
    __shared__ int   nm;
    __shared__ float red[4 * 256];       // 4 KiB
    int g = blockIdx.x >> 5, s = blockIdx.x & 31;
    int t = threadIdx.x, lane = t & 63, w = t >> 6;

    if (t == 0) nm = 0;
    __syncthreads();

    int p0 = s * RANGE;
    for (int i = t; i < RANGE; i += 256) {
        int p = p0 + i;
        if (sub[p] * NL + lab[p] == g) {
            int k = atomicAdd(&nm, 1);
            list[k] = p;
        }
    }
    __syncthreads();
    int n = nm;

    float4 acc = make_float4(0.f, 0.f, 0.f, 0.f);
    for (int i = w * 8; i < n; i += 32) {
        int idx[8];
#pragma unroll
        for (int u = 0; u < 8; ++u) {
            int j = i + u;
            idx[u] = list[(j < n) ? j : (n - 1)];
        }
        float4 x[8];
#pragma unroll
        for (int u = 0; u < 8; ++u) x[u] = X4[(size_t)idx[u] * 64 + lane];
#pragma unroll
        for (int u = 0; u < 8; ++u) {
            if (i + u < n) {
                acc.x += x[u].x; acc.y += x[u].y;
                acc.z += x[u].z; acc.w += x[u].w;
            }
        }
    }
    red[w * 256 + lane * 4 + 0] = acc.x;
    red[w * 256 + lane * 4 + 1] = acc.y;
    red[w * 256 + lane * 4 + 2] = acc.z;
    red[w * 256 + lane * 4 + 3] = acc.w;
    __syncthreads();
    if (t < 128) {                        // fold 4 wave copies + the two views
        float v = 0.f;
        for (int r = 0; r < 4; ++r)
            v += red[r * 256 + t] + red[r * 256 + t + 128];
        part[(size_t)blockIdx.x * 128 + t] = v;
    }
    if (t == 0) cnt[blockIdx.x] = n;
}

// ---------------------------------------------------------------------------
// k_reduce: centroid[g][d] = sum over 32 slice partials / (2n); counts.
// ---------------------------------------------------------------------------
__global__ __launch_bounds__(256) void k_reduce(const float* __restrict__ part,
                                                const int* __restrict__ cnt,
                                                float* __restrict__ centroid,
                                                float* __restrict__ countsf) {
    int i = blockIdx.x * 256 + threadIdx.x;
    if (i >= G_GR * D_DIM) return;
    int g = i >> 7, d = i & 127;
    float v = 0.f;
    int   n = 0;
    for (int s = 0; s < NSLC; ++s) {
        v += part[(size_t)(g * NSLC + s) * 128 + d];
        n += cnt[g * NSLC + s];
    }
    centroid[i] = (n > 0) ? v / (2.0f * (float)n) : 0.f;
    if (d == 0) countsf[g] = 2.0f * (float)n;
}

// ---------------------------------------------------------------------------
// k_dist: natural-order stream over X (perfect coalescing, L3-fed). All 128
// centroids LDS-resident (64 KiB -> 2 blocks/CU, 16 waves/CU). Wave-per-point
// unroll-8; per-view 32-lane shfl butterfly; one LDS atomic per point.
// ---------------------------------------------------------------------------
__global__ __launch_bounds__(512) void k_dist(const float4* __restrict__ X4,
                                              const int* __restrict__ sub,
                                              const int* __restrict__ lab,
                                              const float* __restrict__ centroid,
                                              float* __restrict__ dpart) {
    __shared__ float4 cen4[G_GR * 32];   // 64 KiB: cen4[g*32+q] = dims 4q..4q+3
    __shared__ float  dsum[G_GR];
    int t = threadIdx.x, lane = t & 63, w = t >> 6;

    const float4* c4 = (const float4*)centroid;
    for (int i = t; i < G_GR * 32; i += 512) cen4[i] = c4[i];
    if (t < G_GR) dsum[t] = 0.f;
    __syncthreads();

    int p0 = blockIdx.x * DPTS;
    int q  = lane & 31;
    // 8 waves, wave-per-point, unroll 8 -> each wave covers DPTS/8=32 pts
    for (int i = w * 8; i < DPTS; i += 64) {
        int pg[8];
#pragma unroll
        for (int u = 0; u < 8; ++u) {
            int p = p0 + i + u;
            pg[u] = sub[p] * NL + lab[p];     // broadcast loads (L2-hot)
        }
        float4 x[8];
#pragma unroll
        for (int u = 0; u < 8; ++u)
            x[u] = X4[(size_t)(p0 + i + u) * 64 + lane];
#pragma unroll
        for (int u = 0; u < 8; ++u) {
            float4 c = cen4[pg[u] * 32 + q];
            float dx = x[u].x - c.x, dy = x[u].y - c.y;
            float dz = x[u].z - c.z, dw = x[u].w - c.w;
            float d = dx * dx + dy * dy + dz * dz + dw * dw;
#pragma unroll
            for (int m = 1; m <= 16; m <<= 1) d += __shfl_xor(d, m);
            float sd = sqrtf(sqrtf(d));               // sqrt(||x-c||) per view
            float tot = sd + __shfl_down(sd, 32);     // view0 + view1 at lane 0
            if (lane == 0) atomicAdd(&dsum[pg[u]], tot);
        }
    }
    __syncthreads();
    if (t < G_GR) dpart[(size_t)blockIdx.x * G_GR + t] = dsum[t];
}

// ---------------------------------------------------------------------------
// k_final: single block, 128 threads (thread t = group t).
// ---------------------------------------------------------------------------
__global__ __launch_bounds__(128) void k_final(const float* __restrict__ dpart,
                                               const float* __restrict__ countsf,
                                               const float* __restrict__ centroid,
                                               float* __restrict__ out) {
    __shared__ float srt[G_GR];
    __shared__ float red[G_GR];
    __shared__ float coc[D_DIM];
    int t = threadIdx.x;

    float ds = 0.f;
    for (int b = 0; b < DBLK; ++b) ds += dpart[(size_t)b * G_GR + t];
    float cnt  = countsf[t];
    float dens = (cnt > 1.f) ? (ds / cnt) / logf(cnt + 10.f) : 0.f;

    red[t] = dens;
    __syncthreads();
    for (int s = 64; s > 0; s >>= 1) {
        if (t < s) red[t] = fmaxf(red[t], red[t + s]);
        __syncthreads();
    }
    float dmax = red[0];
    __syncthreads();
    if (!(cnt > 1.f)) dens = dmax;

    srt[t] = dens;
    __syncthreads();
    for (int k = 2; k <= G_GR; k <<= 1) {
        for (int j = k >> 1; j > 0; j >>= 1) {
            int ixj = t ^ j;
            if (ixj > t) {
                float a = srt[t], b = srt[ixj];
                bool up = ((t & k) == 0);
                if ((a > b) == up) { srt[t] = b; srt[ixj] = a; }
            }
            __syncthreads();
        }
    }
    double p10 = 0.10 * 127.0, p90 = 0.90 * 127.0;
    int   i10 = (int)p10,           i90 = (int)p90;
    float f10 = (float)(p10 - i10), f90 = (float)(p90 - i90);
    float lo = srt[i10] + f10 * (srt[i10 + 1] - srt[i10]);
    float hi = srt[i90] + f90 * (srt[i90 + 1] - srt[i90]);
    dens = fminf(fmaxf(dens, lo), hi);

    red[t] = dens;
    __syncthreads();
    for (int s = 64; s > 0; s >>= 1) {
        if (t < s) red[t] += red[t + s];
        __syncthreads();
    }
    float dmean = red[0] / 128.f;
    __syncthreads();
    dens = 0.1f * dens / dmean;

    float cs = 0.f;
    for (int g = 0; g < G_GR; ++g) cs += centroid[g * D_DIM + t];
    coc[t] = cs / 128.f;
    __syncthreads();

    float dot = 0.f;
    for (int d = 0; d < D_DIM; ++d) dot += centroid[t * D_DIM + d] * coc[d];
    float sim = expf(dot / dens);

    red[t] = sim;
    __syncthreads();
    for (int s = 64; s > 0; s >>= 1) {
        if (t < s) red[t] = fmaxf(red[t], red[t + s]);
        __syncthreads();
    }
    float smax = red[0];
    __syncthreads();
    red[t] = sim - smax;
    __syncthreads();
    for (int s = 64; s > 0; s >>= 1) {
        if (t < s) red[t] += red[t + s];
        __syncthreads();
    }
    if (t == 0) out[0] = -(red[0] / 128.f);
}

// ---------------------------------------------------------------------------
extern "C" void kernel_launch(void* const* d_in, const int* in_sizes, int n_in,
                              void* d_out, int out_size, void* d_ws, size_t ws_size,
                              hipStream_t stream) {
    const float4* X4      = (const float4*)d_in[0];
    const int*    subject = (const int*)d_in[1];
    const int*    labels  = (const int*)d_in[2];
    float*        out     = (float*)d_out;
    char*         ws      = (char*)d_ws;

    size_t o = 0;
    float* part     = (float*)(ws + o); o += (size_t)G_GR * NSLC * 128 * 4;  // 2 MiB
    int*   cnt      = (int*)(ws + o);   o += (size_t)G_GR * NSLC * 4;        // 16 KiB
    float* centroid = (float*)(ws + o); o += (size_t)G_GR * D_DIM * 4;       // 64 KiB
    float* countsf  = (float*)(ws + o); o += 512;
    float* dpart    = (float*)(ws + o); o += (size_t)DBLK * G_GR * 4;        // 256 KiB

    k_psum  <<<G_GR * NSLC, 256, 0, stream>>>(X4, subject, labels, part, cnt);
    k_reduce<<<(G_GR * D_DIM + 255) / 256, 256, 0, stream>>>(part, cnt, centroid, countsf);
    k_dist  <<<DBLK, 512, 0, stream>>>(X4, subject, labels, centroid, dpart);
    k_final <<<1, 128, 0, stream>>>(dpart, countsf, centroid, out);
}